// Round 1
// 1293.000 us; speedup vs baseline: 1.0569x; 1.0569x over previous
//
#include <hip/hip_runtime.h>
#include <hip/hip_bf16.h>
#include <cstdint>

typedef __bf16 bf16;
typedef __bf16 bf16x4 __attribute__((ext_vector_type(4)));
typedef __bf16 bf16x8 __attribute__((ext_vector_type(8)));
typedef float  f32x4  __attribute__((ext_vector_type(4)));

#define BTOK 8192
#define FDIM 2048
#define NEXP 16
#define UDIM 2048
#define DMODEL 2048
#define BSTRIDE 8320  // bucket capacity per expert (8192 + 128 pad)

__device__ __forceinline__ void gl2lds16(const void* g, void* l) {
  __builtin_amdgcn_global_load_lds(
      (const __attribute__((address_space(1))) void*)g,
      (__attribute__((address_space(3))) void*)l, 16, 0, 0);
}

// ---------- shared GEMM core: 128x128 tile, BK=32, 256 thr, 16x16x32 bf16 MFMA ----------
// (still used by expert_gemm; gemm_bias has moved to the 256^2 8-phase kernel below)
__device__ __forceinline__ void gemm_core(
    const bf16* __restrict__ aP0, const bf16* __restrict__ aP1,
    const bf16* __restrict__ bP0, const bf16* __restrict__ bP1,
    int Kdim, bf16* As, bf16* Bs, f32x4 acc[4][4])
{
  const int tid  = threadIdx.x;
  const int lane = tid & 63;
  const int wave = tid >> 6;
  const int wm   = (wave >> 1) * 64;
  const int wn   = (wave & 1) * 64;
  const int lhi  = lane >> 4;
  const int llo  = lane & 15;
  bf16* lA0 = As + wave * 512;
  bf16* lA1 = As + 2048 + wave * 512;
  bf16* lB0 = Bs + wave * 512;
  bf16* lB1 = Bs + 2048 + wave * 512;
  for (int k0 = 0; k0 < Kdim; k0 += 32) {
    if (k0) __syncthreads();
    gl2lds16(aP0 + k0, lA0);
    gl2lds16(aP1 + k0, lA1);
    gl2lds16(bP0 + k0, lB0);
    gl2lds16(bP1 + k0, lB1);
    __syncthreads();
    bf16x8 af[4], bv[4];
#pragma unroll
    for (int i = 0; i < 4; ++i)
      af[i] = *(const bf16x8*)(As + (wm + i * 16 + llo) * 32 + lhi * 8);
#pragma unroll
    for (int j = 0; j < 4; ++j)
      bv[j] = *(const bf16x8*)(Bs + (wn + j * 16 + llo) * 32 + lhi * 8);
#pragma unroll
    for (int i = 0; i < 4; ++i)
#pragma unroll
      for (int j = 0; j < 4; ++j)
        acc[i][j] = __builtin_amdgcn_mfma_f32_16x16x32_bf16(af[i], bv[j], acc[i][j], 0, 0, 0);
  }
}

// ================= 256x256 8-phase GEMM (T1+T2+T3/T4+T5) =================
// BM=BN=256, BK=64, 512 threads (8 waves as 2Mx4N), per-wave C = 128x64.
// LDS 128 KiB: 2 buffers x { A: [ks=2][256 rows][32 cols], B: same } bf16,
// st_16x32 swizzle (byte ^= ((byte>>9)&1)<<5) applied via pre-swizzled
// global source (linear global_load_lds dest) + swizzled ds_read addrs.
// Per K-tile: 4 phases, each {ds_read subtile | stage 1 half-tile ->
// barrier -> lgkmcnt(0) -> setprio(1) -> 16 MFMA -> setprio(0) -> barrier}.
// Counted vmcnt(4) once per K-tile (2 half-tiles / 4 loads in flight).
//
// Half-tile stream: prologue t0h0..h3,t1h0,t1h1; group t phases stage
// (t+1)h2,(t+1)h3,(t+2)h0,(t+2)h1.  Safety: A-region reads of buf c finish
// by ph2 (LDA(0) ph1, LDA(4) ph2) before (t+2)h0/h1 restage it (ph3/ph4);
// B-region reads finish by ph3 and are only restaged next group's ph1/ph2.

#define G256_BAR()  __builtin_amdgcn_s_barrier()
#define G256_LGK0() asm volatile("s_waitcnt lgkmcnt(0)" ::: "memory")

#define G256_STAGE(h, kt) do {                                               \
    const bf16* sb_ = ((h) < 2) ? Ab : Bb;                                   \
    const int ro_ = (((kt) & 1) << 16) + (((h) >= 2) ? 32768 : 0)            \
                    + (((h) & 1) << 13);                                     \
    _Pragma("unroll")                                                        \
    for (int l_ = 0; l_ < 2; ++l_) {                                         \
      const int u_   = (((h) & 1) << 9) + (l_ << 10) + tid;                  \
      const int row_ = (u_ & 1023) >> 2;                                     \
      const int ch_  = ((u_ >> 10) << 2)                                     \
                       + ((u_ & 3) ^ (((row_ >> 3) & 1) << 1));              \
      const bf16* s_ = sb_ + (size_t)(row_ * Kdim + (kt) * 64 + ch_ * 8);    \
      char* d_ = smem + ro_ + (l_ << 14) + ((tid & ~63) << 4);               \
      gl2lds16(s_, d_);                                                      \
    }                                                                        \
  } while (0)

#define G256_LDA(I0)                                                         \
  _Pragma("unroll") for (int i_ = 0; i_ < 4; ++i_)                           \
  _Pragma("unroll") for (int ks_ = 0; ks_ < 2; ++ks_)                        \
    Ar[(I0) + i_][ks_] =                                                     \
        *(const bf16x8*)(smem + c + aOff[(I0) + i_] + ks_ * 16384);

#define G256_LDB(J0)                                                         \
  _Pragma("unroll") for (int jj_ = 0; jj_ < 2; ++jj_)                        \
  _Pragma("unroll") for (int ks_ = 0; ks_ < 2; ++ks_)                        \
    Br[jj_][ks_] =                                                           \
        *(const bf16x8*)(smem + c + bOff[(J0) + jj_] + ks_ * 16384);

#define G256_MFMA16(I0, J0)                                                  \
  _Pragma("unroll") for (int i_ = 0; i_ < 4; ++i_)                           \
  _Pragma("unroll") for (int jj_ = 0; jj_ < 2; ++jj_)                        \
  _Pragma("unroll") for (int ks_ = 0; ks_ < 2; ++ks_)                        \
    acc[(I0) + i_][(J0) + jj_] = __builtin_amdgcn_mfma_f32_16x16x32_bf16(    \
        Ar[(I0) + i_][ks_], Br[jj_][ks_], acc[(I0) + i_][(J0) + jj_], 0, 0, 0);

template <typename OutT>
__global__ __launch_bounds__(512, 2) void gemm256(
    const bf16* __restrict__ A, const bf16* __restrict__ Bt,
    const float* __restrict__ bias, OutT* __restrict__ C,
    int M, int N, int Kdim)
{
  extern __shared__ __align__(16) char smem[];  // 131072 bytes
  const int tid  = threadIdx.x;
  const int lane = tid & 63;
  const int wave = tid >> 6;
  const int wm   = (wave >> 2) << 7;   // 0 / 128
  const int wn   = (wave & 3) << 6;    // 0 / 64 / 128 / 192
  const int lhi  = lane >> 4, llo = lane & 15;

  // T1: bijective XCD swizzle on 1-D grid (nwg % 8 == 0 for both call sites)
  const int nbx = N >> 8;
  const int nwg = (M >> 8) * nbx;
  const int q8  = nwg >> 3;
  const int bid = (int)blockIdx.x;
  const int swz = (bid & 7) * q8 + (bid >> 3);
  const int mBase = (swz / nbx) << 8;
  const int nBase = (swz % nbx) << 8;

  const bf16* Ab = A + (size_t)mBase * Kdim;
  const bf16* Bb = Bt + (size_t)nBase * Kdim;
  const int NT = Kdim >> 6;

  // swizzled per-lane LDS read byte offsets (within one buffer)
  int aOff[8], bOff[4];
#pragma unroll
  for (int i = 0; i < 8; ++i) {
    const int row = wm + i * 16 + llo;
    aOff[i] = (row * 64 + lhi * 16) ^ (((row >> 3) & 1) << 5);
  }
#pragma unroll
  for (int j = 0; j < 4; ++j) {
    const int row = wn + j * 16 + llo;
    bOff[j] = 32768 + ((row * 64 + lhi * 16) ^ (((row >> 3) & 1) << 5));
  }

  f32x4 acc[8][4];
  const f32x4 zero = {0.f, 0.f, 0.f, 0.f};
#pragma unroll
  for (int i = 0; i < 8; ++i)
#pragma unroll
    for (int j = 0; j < 4; ++j) acc[i][j] = zero;

  bf16x8 Ar[8][2], Br[2][2];

  // prologue: tile0 fully + tile1 h0,h1; wait tile0 resident (4 loads left)
  G256_STAGE(0, 0); G256_STAGE(1, 0); G256_STAGE(2, 0); G256_STAGE(3, 0);
  G256_STAGE(0, 1); G256_STAGE(1, 1);
  asm volatile("s_waitcnt vmcnt(4)" ::: "memory");
  G256_BAR();

#pragma unroll 1
  for (int t = 0; t < NT; ++t) {
    const int c = (t & 1) << 16;
    const bool p1 = (t + 1 < NT), p2 = (t + 2 < NT);
    // ---- phase 1: A-lo + B-lo reads; MFMA (A-lo x B-lo)
    G256_LDA(0); G256_LDB(0);
    if (p1) G256_STAGE(2, t + 1);
    G256_BAR(); G256_LGK0();
    __builtin_amdgcn_s_setprio(1); G256_MFMA16(0, 0); __builtin_amdgcn_s_setprio(0);
    G256_BAR();
    // ---- phase 2: A-hi reads; MFMA (A-hi x B-lo)
    G256_LDA(4);
    if (p1) G256_STAGE(3, t + 1);
    G256_BAR(); G256_LGK0();
    __builtin_amdgcn_s_setprio(1); G256_MFMA16(4, 0); __builtin_amdgcn_s_setprio(0);
    G256_BAR();
    // ---- phase 3: B-hi reads; MFMA (A-hi x B-hi)
    G256_LDB(2);
    if (p2) G256_STAGE(0, t + 2);
    G256_BAR(); G256_LGK0();
    __builtin_amdgcn_s_setprio(1); G256_MFMA16(4, 2); __builtin_amdgcn_s_setprio(0);
    G256_BAR();
    // ---- phase 4: MFMA (A-lo x B-hi); counted vmcnt at tile boundary
    if (p2) G256_STAGE(1, t + 2);
    G256_BAR();
    __builtin_amdgcn_s_setprio(1); G256_MFMA16(0, 2); __builtin_amdgcn_s_setprio(0);
    if (p2) { asm volatile("s_waitcnt vmcnt(4)" ::: "memory"); }
    else    { asm volatile("s_waitcnt vmcnt(0)" ::: "memory"); }
    G256_BAR();
  }

  // epilogue: C = acc + bias
#pragma unroll
  for (int i = 0; i < 8; ++i) {
#pragma unroll
    for (int r = 0; r < 4; ++r) {
      const int row = mBase + wm + i * 16 + lhi * 4 + r;
#pragma unroll
      for (int j = 0; j < 4; ++j) {
        const int col = nBase + wn + j * 16 + llo;
        C[(size_t)row * N + col] = (OutT)(acc[i][j][r] + bias[col]);
      }
    }
  }
}

// ---------- transpose fp32 [R][C] -> bf16 [C][R], 64x64 tiles ----------
__global__ __launch_bounds__(256) void transpose_kernel(
    const float* __restrict__ in, bf16* __restrict__ out,
    int R, int C, long long inZ, long long outZ)
{
  __shared__ float tile[64][65];
  const long long zi = (long long)blockIdx.z * inZ;
  const long long zo = (long long)blockIdx.z * outZ;
  const int r0 = blockIdx.y * 64, c0 = blockIdx.x * 64;
  const int tid = threadIdx.x;
  const int tr = tid >> 4;
  const int tc = (tid & 15) * 4;
#pragma unroll
  for (int it = 0; it < 4; ++it) {
    int r = it * 16 + tr;
    float4 v = *(const float4*)(in + zi + (size_t)(r0 + r) * C + c0 + tc);
    tile[r][tc] = v.x; tile[r][tc + 1] = v.y; tile[r][tc + 2] = v.z; tile[r][tc + 3] = v.w;
  }
  __syncthreads();
#pragma unroll
  for (int it = 0; it < 4; ++it) {
    int c = it * 16 + tr;
    bf16x4 ov;
    ov[0] = (bf16)tile[tc + 0][c];
    ov[1] = (bf16)tile[tc + 1][c];
    ov[2] = (bf16)tile[tc + 2][c];
    ov[3] = (bf16)tile[tc + 3][c];
    *(bf16x4*)(out + zo + (size_t)(c0 + c) * R + r0 + tc) = ov;
  }
}

__global__ __launch_bounds__(256) void concat_bias(
    const float* __restrict__ bq, const float* __restrict__ bk,
    const float* __restrict__ bv, float* __restrict__ out)
{
  int i = blockIdx.x * 256 + threadIdx.x;
  if (i < 2048) out[i] = bq[i];
  else if (i < 4096) out[i] = bk[i - 2048];
  else if (i < 6144) out[i] = bv[i - 4096];
}

// ---------- router: logits, softmax, top-2, bucket scatter; fuses x->bf16 ----------
__global__ __launch_bounds__(256) void router_kernel(
    const float* __restrict__ x, const float* __restrict__ rw,
    const float* __restrict__ rb, bf16* __restrict__ xb,
    int* __restrict__ cnt, int* __restrict__ btok, float* __restrict__ bgate)
{
  const int tid = threadIdx.x, lane = tid & 63, wave = tid >> 6;
  const int tokBase = blockIdx.x * 16 + wave * 4;
  float acc[4][16];
#pragma unroll
  for (int t = 0; t < 4; ++t)
#pragma unroll
    for (int e = 0; e < 16; ++e) acc[t][e] = 0.f;

#pragma unroll 1
  for (int c = 0; c < 8; ++c) {
    const int f = c * 256 + lane * 4;
    float xv[4][4];
#pragma unroll
    for (int t = 0; t < 4; ++t) {
      float4 v = *(const float4*)(x + (size_t)(tokBase + t) * FDIM + f);
      xv[t][0] = v.x; xv[t][1] = v.y; xv[t][2] = v.z; xv[t][3] = v.w;
      bf16x4 b; b[0] = (bf16)v.x; b[1] = (bf16)v.y; b[2] = (bf16)v.z; b[3] = (bf16)v.w;
      *(bf16x4*)(xb + (size_t)(tokBase + t) * FDIM + f) = b;
    }
#pragma unroll
    for (int ff = 0; ff < 4; ++ff) {
      const float* rwr = rw + (size_t)(f + ff) * 16;
      float4 r0 = *(const float4*)(rwr);
      float4 r1 = *(const float4*)(rwr + 4);
      float4 r2 = *(const float4*)(rwr + 8);
      float4 r3 = *(const float4*)(rwr + 12);
      float rr[16] = {r0.x, r0.y, r0.z, r0.w, r1.x, r1.y, r1.z, r1.w,
                      r2.x, r2.y, r2.z, r2.w, r3.x, r3.y, r3.z, r3.w};
#pragma unroll
      for (int t = 0; t < 4; ++t) {
        float xs = xv[t][ff];
#pragma unroll
        for (int e = 0; e < 16; ++e) acc[t][e] = fmaf(xs, rr[e], acc[t][e]);
      }
    }
  }
#pragma unroll
  for (int t = 0; t < 4; ++t)
#pragma unroll
    for (int e = 0; e < 16; ++e) {
      float v = acc[t][e];
      v += __shfl_xor(v, 32); v += __shfl_xor(v, 16); v += __shfl_xor(v, 8);
      v += __shfl_xor(v, 4);  v += __shfl_xor(v, 2);  v += __shfl_xor(v, 1);
      acc[t][e] = v;
    }
  if (lane < 4) {
    const int tok = tokBase + lane;
    float lg[16];
#pragma unroll
    for (int e = 0; e < 16; ++e) lg[e] = acc[lane][e] + rb[e];
    float mx = lg[0];
#pragma unroll
    for (int e = 1; e < 16; ++e) mx = fmaxf(mx, lg[e]);
    float p[16], s = 0.f;
#pragma unroll
    for (int e = 0; e < 16; ++e) { p[e] = __expf(lg[e] - mx); s += p[e]; }
    const float inv = 1.f / s;
    int e0 = 0;
#pragma unroll
    for (int e = 1; e < 16; ++e) if (lg[e] > lg[e0]) e0 = e;
    int e1 = (e0 == 0) ? 1 : 0;
#pragma unroll
    for (int e = 0; e < 16; ++e) { if (e != e0 && lg[e] > lg[e1]) e1 = e; }
    const float g0 = p[e0] * inv, g1 = p[e1] * inv;
    int s0 = atomicAdd(cnt + e0, 1);
    btok[e0 * BSTRIDE + s0] = tok; bgate[e0 * BSTRIDE + s0] = g0;
    int s1 = atomicAdd(cnt + e1, 1);
    btok[e1 * BSTRIDE + s1] = tok; bgate[e1 * BSTRIDE + s1] = g1;
  }
}

// ---------- pad buckets to x128, build tile map + pass boundaries ----------
__global__ void finalize_buckets(const int* __restrict__ cnt, int* __restrict__ btok,
                                 float* __restrict__ bgate, int2* __restrict__ tmap,
                                 int* __restrict__ ntl3)
{
  __shared__ int tilesS[16];
  const int tid = threadIdx.x;
  if (tid < 16) tilesS[tid] = (cnt[tid] + 127) >> 7;
  __syncthreads();
  for (int e = 0; e < 16; ++e) {
    int c = cnt[e], end = tilesS[e] * 128;
    for (int i = c + tid; i < end; i += 256) {
      btok[e * BSTRIDE + i] = 0;
      bgate[e * BSTRIDE + i] = 0.f;
    }
  }
  if (tid == 0) {
    int s = 0, sA = 0;
    for (int e = 0; e < 16; ++e) {
      for (int m = 0; m < tilesS[e]; ++m) { tmap[s] = make_int2(e, m * 128); ++s; }
      if (e == 7) sA = s;
    }
    ntl3[0] = 0; ntl3[1] = sA; ntl3[2] = s;
  }
}

// ---------- gathered expert GEMM: relu(x@We + be) * gate -> atomicAdd moe32 ----------
__global__ __launch_bounds__(256) void expert_gemm(
    const bf16* __restrict__ xb, const bf16* __restrict__ ewt,
    const float* __restrict__ eb, const int* __restrict__ btok,
    const float* __restrict__ bgate, const int2* __restrict__ tmap,
    const int* __restrict__ ntl3, int passIdx, int e0glob,
    float* __restrict__ moe32)
{
  __shared__ __align__(16) bf16 As[4096];
  __shared__ __align__(16) bf16 Bs[4096];
  __shared__ int   tokS[128];
  __shared__ float gateS[128];
  const int tstart = ntl3[passIdx], tend = ntl3[passIdx + 1];
  const int t = tstart + blockIdx.y;
  if (t >= tend) return;
  const int2 mp = tmap[t];
  const int e = mp.x, rowStart = mp.y;
  const int nBase = blockIdx.x * 128;
  const int tid = threadIdx.x;
  const int bbase = e * BSTRIDE + rowStart;
  if (tid < 128) {
    tokS[tid]  = btok[bbase + tid];
    gateS[tid] = bgate[bbase + tid];
  }
  const int rr0 = tid >> 2, rr1 = 64 + rr0;
  const int ch = (tid & 3) * 8;
  const int t0 = btok[bbase + rr0];
  const int t1 = btok[bbase + rr1];
  const bf16* aP0 = xb + (size_t)t0 * FDIM + ch;
  const bf16* aP1 = xb + (size_t)t1 * FDIM + ch;
  const bf16* Bb = ewt + ((size_t)(e - e0glob) << 22);
  const bf16* bP0 = Bb + (size_t)(nBase + rr0) * FDIM + ch;
  const bf16* bP1 = Bb + (size_t)(nBase + rr1) * FDIM + ch;

  f32x4 acc[4][4];
  const f32x4 zero = {0.f, 0.f, 0.f, 0.f};
#pragma unroll
  for (int i = 0; i < 4; ++i)
#pragma unroll
    for (int j = 0; j < 4; ++j) acc[i][j] = zero;

  gemm_core(aP0, aP1, bP0, bP1, FDIM, As, Bs, acc);

  const int lane = tid & 63, wave = tid >> 6;
  const int wm = (wave >> 1) * 64, wn = (wave & 1) * 64;
  const int lhi = lane >> 4, llo = lane & 15;
#pragma unroll
  for (int i = 0; i < 4; ++i) {
#pragma unroll
    for (int r = 0; r < 4; ++r) {
      const int rl = wm + i * 16 + lhi * 4 + r;
      const int tok = tokS[rl];
      const float g = gateS[rl];
      if (g != 0.f) {
#pragma unroll
        for (int j = 0; j < 4; ++j) {
          const int col = nBase + wn + j * 16 + llo;
          float v = acc[i][j][r] + eb[e * UDIM + col];
          v = fmaxf(v, 0.f);
          atomicAdd(moe32 + (size_t)tok * UDIM + col, v * g);
        }
      }
    }
  }
}

__global__ __launch_bounds__(256) void f32_to_bf16_vec(
    const float* __restrict__ in, bf16* __restrict__ out, int n4)
{
  int i = blockIdx.x * 256 + threadIdx.x;
  if (i >= n4) return;
  float4 v = ((const float4*)in)[i];
  bf16x4 b; b[0] = (bf16)v.x; b[1] = (bf16)v.y; b[2] = (bf16)v.z; b[3] = (bf16)v.w;
  ((bf16x4*)out)[i] = b;
}

// ---------- per-token MLA: scores, softmax over 16 heads, attn*v ----------
__global__ __launch_bounds__(256) void attn_kernel(
    const bf16* __restrict__ qkv, bf16* __restrict__ aout)
{
  const int lane = threadIdx.x & 63, wave = threadIdx.x >> 6;
  const int tok = blockIdx.x * 4 + wave;
  const bf16* base = qkv + (size_t)tok * (3 * DMODEL);
  const int h = lane >> 2, part = lane & 3;
  const int off = h * 128 + part * 32;
  float dot = 0.f;
#pragma unroll
  for (int c = 0; c < 4; ++c) {
    bf16x8 qv = *(const bf16x8*)(base + off + c * 8);
    bf16x8 kv = *(const bf16x8*)(base + DMODEL + off + c * 8);
#pragma unroll
    for (int u = 0; u < 8; ++u) dot += (float)qv[u] * (float)kv[u];
  }
  dot += __shfl_xor(dot, 1);
  dot += __shfl_xor(dot, 2);
  const float score = dot * 0.08838834764831845f;  // 1/sqrt(128)
  float sc[16];
#pragma unroll
  for (int e = 0; e < 16; ++e) sc[e] = __shfl(score, e * 4);
  float mx = sc[0];
#pragma unroll
  for (int e = 1; e < 16; ++e) mx = fmaxf(mx, sc[e]);
  float sum = 0.f, mex = 0.f;
#pragma unroll
  for (int e = 0; e < 16; ++e) {
    float ex = __expf(sc[e] - mx);
    sum += ex;
    mex = (e == h) ? ex : mex;
  }
  const float attn = mex / sum;
  bf16* op = aout + (size_t)tok * DMODEL + off;
#pragma unroll
  for (int c = 0; c < 4; ++c) {
    bf16x8 vv = *(const bf16x8*)(base + 2 * DMODEL + off + c * 8);
    bf16x8 ov;
#pragma unroll
    for (int u = 0; u < 8; ++u) ov[u] = (bf16)(attn * (float)vv[u]);
    *(bf16x8*)(op + c * 8) = ov;
  }
}

extern "C" void kernel_launch(void* const* d_in, const int* in_sizes, int n_in,
                              void* d_out, int out_size, void* d_ws, size_t ws_size,
                              hipStream_t stream) {
  const float* x   = (const float*)d_in[0];
  const float* rw  = (const float*)d_in[1];
  const float* rb  = (const float*)d_in[2];
  const float* ew  = (const float*)d_in[3];
  const float* eb  = (const float*)d_in[4];
  const float* wq  = (const float*)d_in[5];
  const float* bq  = (const float*)d_in[6];
  const float* wk  = (const float*)d_in[7];
  const float* bk  = (const float*)d_in[8];
  const float* wv  = (const float*)d_in[9];
  const float* bv  = (const float*)d_in[10];
  const float* wo_ = (const float*)d_in[11];
  const float* bo  = (const float*)d_in[12];
  float* out = (float*)d_out;

  // Allow 128 KiB dynamic LDS for the 256^2 8-phase GEMM.
  static bool attrSet = false;
  if (!attrSet) {
    hipFuncSetAttribute((const void*)gemm256<bf16>,
                        hipFuncAttributeMaxDynamicSharedMemorySize, 131072);
    hipFuncSetAttribute((const void*)gemm256<float>,
                        hipFuncAttributeMaxDynamicSharedMemorySize, 131072);
    attrSet = true;
  }

  uint8_t* ws = (uint8_t*)d_ws;
  // Static overlapped layout, peak ~193.2 MiB.
  //  [0,64M):    ewt half (experts e0..e0+7)  ->  moeb [0,32M)  ->  aout [0,32M)
  //  [64M,160M): moe32 [64M,128M)             ->  qkv  [64M,160M)
  //  [160M,192M):xb                           ->  qkvt [160M,184M) + wot [184M,192M)
  //  [192M,...): misc (bqkv, cnt, ntl3, tmap, btok, bgate)
  bf16*  ewt   = (bf16*)(ws);
  bf16*  moeb  = (bf16*)(ws);
  bf16*  aout  = (bf16*)(ws);
  float* moe32 = (float*)(ws + 67108864);
  bf16*  qkv   = (bf16*)(ws + 67108864);
  bf16*  xb    = (bf16*)(ws + 167772160);
  bf16*  qkvt  = (bf16*)(ws + 167772160);
  bf16*  wot   = (bf16*)(ws + 167772160 + 25165824);
  uint8_t* misc = ws + 201326592;
  float* bqkv  = (float*)(misc);            misc += 24576;
  int*   cnt   = (int*)(misc);              misc += 256;
  int*   ntl3  = (int*)(misc);              misc += 256;
  int2*  tmap  = (int2*)(misc);             misc += 2048;
  int*   btok  = (int*)(misc);              misc += 532480;
  float* bgate = (float*)(misc);            misc += 532480;

  hipMemsetAsync(moe32, 0, 67108864, stream);
  hipMemsetAsync(cnt, 0, 64, stream);

  // experts 0..7 -> ewt (bf16, [e][U][F])
  transpose_kernel<<<dim3(32, 32, 8), 256, 0, stream>>>(ew, ewt, FDIM, UDIM, 4194304LL, 4194304LL);
  router_kernel<<<512, 256, 0, stream>>>(x, rw, rb, xb, cnt, btok, bgate);
  finalize_buckets<<<1, 256, 0, stream>>>(cnt, btok, bgate, tmap, ntl3);
  expert_gemm<<<dim3(16, 136), 256, 0, stream>>>(xb, ewt, eb, btok, bgate, tmap, ntl3, 0, 0, moe32);
  // experts 8..15 into the same 64MB buffer
  transpose_kernel<<<dim3(32, 32, 8), 256, 0, stream>>>(ew + (size_t)8 * 4194304, ewt, FDIM, UDIM, 4194304LL, 4194304LL);
  expert_gemm<<<dim3(16, 136), 256, 0, stream>>>(xb, ewt, eb, btok, bgate, tmap, ntl3, 1, 8, moe32);

  // moe32 -> bf16 (ewt dead; moeb at ws+0)
  f32_to_bf16_vec<<<16384, 256, 0, stream>>>(moe32, moeb, 4194304);

  // xb dead now: transpose qkv/wo weights into its region
  transpose_kernel<<<dim3(32, 32, 1), 256, 0, stream>>>(wq, qkvt,            UDIM, DMODEL, 0, 0);
  transpose_kernel<<<dim3(32, 32, 1), 256, 0, stream>>>(wk, qkvt + 4194304,  UDIM, DMODEL, 0, 0);
  transpose_kernel<<<dim3(32, 32, 1), 256, 0, stream>>>(wv, qkvt + 8388608,  UDIM, DMODEL, 0, 0);
  transpose_kernel<<<dim3(32, 32, 1), 256, 0, stream>>>(wo_, wot, DMODEL, DMODEL, 0, 0);
  concat_bias<<<24, 256, 0, stream>>>(bq, bk, bv, bqkv);

  // fused QKV GEMM: [8192 x 6144 x 2048] -> 256^2 8-phase kernel (768 blocks)
  gemm256<bf16><<<dim3(768), 512, 131072, stream>>>(moeb, qkvt, bqkv, qkv, BTOK, 3 * DMODEL, UDIM);
  attn_kernel<<<2048, 256, 0, stream>>>(qkv, aout);
  // output projection: [8192 x 2048 x 2048] + bo -> fp32 d_out (256 blocks)
  gemm256<float><<<dim3(256), 512, 131072, stream>>>(aout, wot, bo, out, BTOK, DMODEL, 2048);
}

// Round 2
// 1121.086 us; speedup vs baseline: 1.2189x; 1.1533x over previous
//
#include <hip/hip_runtime.h>
#include <hip/hip_bf16.h>
#include <cstdint>

typedef __bf16 bf16;
typedef __bf16 bf16x4 __attribute__((ext_vector_type(4)));
typedef __bf16 bf16x8 __attribute__((ext_vector_type(8)));
typedef float  f32x4  __attribute__((ext_vector_type(4)));

#define BTOK 8192
#define FDIM 2048
#define NEXP 16
#define UDIM 2048
#define DMODEL 2048
#define BSTRIDE 8448  // bucket capacity per expert (8192 + 256 pad), multiple of 256

__device__ __forceinline__ void gl2lds16(const void* g, void* l) {
  __builtin_amdgcn_global_load_lds(
      (const __attribute__((address_space(1))) void*)g,
      (__attribute__((address_space(3))) void*)l, 16, 0, 0);
}

// ================= 256x256 8-phase GEMM core (T1+T2+T3/T4+T5) =================
// BM=BN=256, BK=64, 512 threads (8 waves as 2Mx4N), per-wave C = 128x64.
// LDS 128 KiB: 2 buffers x { A: [ks=2][256 rows][32 cols], B: same } bf16,
// st_16x32 swizzle (chunk ^= ((row>>3)&1)<<1) applied via pre-swizzled
// global source (linear global_load_lds dest) + swizzled ds_read addrs.
// Per K-tile: 4 phases {ds_read subtile | stage 1 half-tile -> barrier ->
// lgkmcnt(0) -> setprio(1) -> 16 MFMA -> setprio(0) -> barrier}.
// Counted vmcnt(4) once per K-tile; drain only at the end.

#define G256_BAR()  __builtin_amdgcn_s_barrier()
#define G256_LGK0() asm volatile("s_waitcnt lgkmcnt(0)" ::: "memory")

#define G256_STAGE(h, kt) do {                                               \
    const bf16* sb_ = ((h) < 2) ? Ab : Bb;                                   \
    const int ro_ = (((kt) & 1) << 16) + (((h) >= 2) ? 32768 : 0)            \
                    + (((h) & 1) << 13);                                     \
    _Pragma("unroll")                                                        \
    for (int l_ = 0; l_ < 2; ++l_) {                                         \
      const int u_   = (((h) & 1) << 9) + (l_ << 10) + tid;                  \
      const int row_ = (u_ & 1023) >> 2;                                     \
      const int ch_  = ((u_ >> 10) << 2)                                     \
                       + ((u_ & 3) ^ (((row_ >> 3) & 1) << 1));              \
      const bf16* s_ = sb_ + (size_t)(row_ * Kdim + (kt) * 64 + ch_ * 8);    \
      char* d_ = smem + ro_ + (l_ << 14) + ((tid & ~63) << 4);               \
      gl2lds16(s_, d_);                                                      \
    }                                                                        \
  } while (0)

// expert variant: per-thread gathered row base pointers (aRow0/aRow1 for A
// halves, bRow0/bRow1 for B halves), same LDS layout/swizzle as G256_STAGE.
#define E256_STAGE(h, kt) do {                                               \
    const bf16* rp_ = ((h) == 0) ? aRow0 : ((h) == 1) ? aRow1                \
                      : ((h) == 2) ? bRow0 : bRow1;                          \
    const int ro_ = (((kt) & 1) << 16) + (((h) >= 2) ? 32768 : 0)            \
                    + (((h) & 1) << 13);                                     \
    _Pragma("unroll")                                                        \
    for (int l_ = 0; l_ < 2; ++l_) {                                         \
      const bf16* s_ = rp_ + (kt) * 64 + (l_ * 4 + chsw) * 8;                \
      char* d_ = smem + ro_ + (l_ << 14) + ((tid & ~63) << 4);               \
      gl2lds16(s_, d_);                                                      \
    }                                                                        \
  } while (0)

#define G256_LDA(I0)                                                         \
  _Pragma("unroll") for (int i_ = 0; i_ < 4; ++i_)                           \
  _Pragma("unroll") for (int ks_ = 0; ks_ < 2; ++ks_)                        \
    Ar[(I0) + i_][ks_] =                                                     \
        *(const bf16x8*)(smem + c + aOff[(I0) + i_] + ks_ * 16384);

#define G256_LDB(J0)                                                         \
  _Pragma("unroll") for (int jj_ = 0; jj_ < 2; ++jj_)                        \
  _Pragma("unroll") for (int ks_ = 0; ks_ < 2; ++ks_)                        \
    Br[jj_][ks_] =                                                           \
        *(const bf16x8*)(smem + c + bOff[(J0) + jj_] + ks_ * 16384);

#define G256_MFMA16(I0, J0)                                                  \
  _Pragma("unroll") for (int i_ = 0; i_ < 4; ++i_)                           \
  _Pragma("unroll") for (int jj_ = 0; jj_ < 2; ++jj_)                        \
  _Pragma("unroll") for (int ks_ = 0; ks_ < 2; ++ks_)                        \
    acc[(I0) + i_][(J0) + jj_] = __builtin_amdgcn_mfma_f32_16x16x32_bf16(    \
        Ar[(I0) + i_][ks_], Br[jj_][ks_], acc[(I0) + i_][(J0) + jj_], 0, 0, 0);

// K-loop phases shared by both 256^2 kernels (STAGE_M = staging macro).
#define G256_OFFSETS()                                                       \
  int aOff[8], bOff[4];                                                      \
  _Pragma("unroll")                                                          \
  for (int i = 0; i < 8; ++i) {                                              \
    const int row = wm + i * 16 + llo;                                       \
    aOff[i] = (row * 64 + lhi * 16) ^ (((row >> 3) & 1) << 5);               \
  }                                                                          \
  _Pragma("unroll")                                                          \
  for (int j = 0; j < 4; ++j) {                                              \
    const int row = wn + j * 16 + llo;                                       \
    bOff[j] = 32768 + ((row * 64 + lhi * 16) ^ (((row >> 3) & 1) << 5));     \
  }

#define G256_KLOOP(STAGE_M, NT)                                              \
  STAGE_M(0, 0); STAGE_M(1, 0); STAGE_M(2, 0); STAGE_M(3, 0);                \
  STAGE_M(0, 1); STAGE_M(1, 1);                                              \
  asm volatile("s_waitcnt vmcnt(4)" ::: "memory");                           \
  G256_BAR();                                                                \
  _Pragma("unroll 1")                                                        \
  for (int t = 0; t < (NT); ++t) {                                           \
    const int c = (t & 1) << 16;                                             \
    const bool p1 = (t + 1 < (NT)), p2 = (t + 2 < (NT));                     \
    G256_LDA(0); G256_LDB(0);                                                \
    if (p1) STAGE_M(2, t + 1);                                               \
    G256_BAR(); G256_LGK0();                                                 \
    __builtin_amdgcn_s_setprio(1); G256_MFMA16(0, 0); __builtin_amdgcn_s_setprio(0); \
    G256_BAR();                                                              \
    G256_LDA(4);                                                             \
    if (p1) STAGE_M(3, t + 1);                                               \
    G256_BAR(); G256_LGK0();                                                 \
    __builtin_amdgcn_s_setprio(1); G256_MFMA16(4, 0); __builtin_amdgcn_s_setprio(0); \
    G256_BAR();                                                              \
    G256_LDB(2);                                                             \
    if (p2) STAGE_M(0, t + 2);                                               \
    G256_BAR(); G256_LGK0();                                                 \
    __builtin_amdgcn_s_setprio(1); G256_MFMA16(4, 2); __builtin_amdgcn_s_setprio(0); \
    G256_BAR();                                                              \
    if (p2) STAGE_M(1, t + 2);                                               \
    G256_BAR();                                                              \
    __builtin_amdgcn_s_setprio(1); G256_MFMA16(0, 2); __builtin_amdgcn_s_setprio(0); \
    if (p2) { asm volatile("s_waitcnt vmcnt(4)" ::: "memory"); }             \
    else    { asm volatile("s_waitcnt vmcnt(0)" ::: "memory"); }             \
    G256_BAR();                                                              \
  }

template <typename OutT>
__global__ __launch_bounds__(512, 2) void gemm256(
    const bf16* __restrict__ A, const bf16* __restrict__ Bt,
    const float* __restrict__ bias, OutT* __restrict__ C,
    int M, int N, int Kdim)
{
  extern __shared__ __align__(16) char smem[];  // 131072 bytes
  const int tid  = threadIdx.x;
  const int lane = tid & 63;
  const int wave = tid >> 6;
  const int wm   = (wave >> 2) << 7;   // 0 / 128
  const int wn   = (wave & 3) << 6;    // 0 / 64 / 128 / 192
  const int lhi  = lane >> 4, llo = lane & 15;

  // T1: bijective XCD swizzle on 1-D grid (nwg % 8 == 0 for both call sites)
  const int nbx = N >> 8;
  const int nwg = (M >> 8) * nbx;
  const int q8  = nwg >> 3;
  const int bid = (int)blockIdx.x;
  const int swz = (bid & 7) * q8 + (bid >> 3);
  const int mBase = (swz / nbx) << 8;
  const int nBase = (swz % nbx) << 8;

  const bf16* Ab = A + (size_t)mBase * Kdim;
  const bf16* Bb = Bt + (size_t)nBase * Kdim;
  const int NT = Kdim >> 6;

  G256_OFFSETS();

  f32x4 acc[8][4];
  const f32x4 zero = {0.f, 0.f, 0.f, 0.f};
#pragma unroll
  for (int i = 0; i < 8; ++i)
#pragma unroll
    for (int j = 0; j < 4; ++j) acc[i][j] = zero;

  bf16x8 Ar[8][2], Br[2][2];

  G256_KLOOP(G256_STAGE, NT);

  // epilogue: C = acc + bias
#pragma unroll
  for (int i = 0; i < 8; ++i) {
#pragma unroll
    for (int r = 0; r < 4; ++r) {
      const int row = mBase + wm + i * 16 + lhi * 4 + r;
#pragma unroll
      for (int j = 0; j < 4; ++j) {
        const int col = nBase + wn + j * 16 + llo;
        C[(size_t)row * N + col] = (OutT)(acc[i][j][r] + bias[col]);
      }
    }
  }
}

// ---------- expert GEMM, 256^2 8-phase, gathered A rows, bf16 slot output ----------
// eout[slot][2048] = relu(x[tok(slot)] @ We + be)   (no gate, no atomics)
__global__ __launch_bounds__(512, 2) void expert_gemm256(
    const bf16* __restrict__ xb, const bf16* __restrict__ ewt,
    const float* __restrict__ eb, const int* __restrict__ btok,
    const int2* __restrict__ tmap, const int* __restrict__ ntl3,
    const int* __restrict__ slotBase, int passIdx, int e0glob,
    bf16* __restrict__ eout)
{
  extern __shared__ __align__(16) char smem[];  // 131072 bytes
  const int tstart = ntl3[passIdx], tend = ntl3[passIdx + 1];
  const int t = tstart + (int)blockIdx.y;
  if (t >= tend) return;
  const int2 mp = tmap[t];
  const int e = mp.x, rowStart = mp.y;
  const int nBase = (int)blockIdx.x << 8;
  const int tid  = threadIdx.x;
  const int lane = tid & 63;
  const int wave = tid >> 6;
  const int wm   = (wave >> 2) << 7;
  const int wn   = (wave & 3) << 6;
  const int lhi  = lane >> 4, llo = lane & 15;

  const int r0 = tid >> 2;
  const int bbase = e * BSTRIDE + rowStart;
  // per-thread gathered source rows (A halves) + weight rows (B halves)
  const bf16* aRow0 = xb + (size_t)btok[bbase + r0] * FDIM;
  const bf16* aRow1 = xb + (size_t)btok[bbase + 128 + r0] * FDIM;
  const bf16* Bb = ewt + ((size_t)(e - e0glob) << 22);
  const bf16* bRow0 = Bb + (size_t)(nBase + r0) * FDIM;
  const bf16* bRow1 = Bb + (size_t)(nBase + 128 + r0) * FDIM;
  // swizzled 16B-chunk index (same parity for row and row+128)
  const int chsw = (tid & 3) ^ (((r0 >> 3) & 1) << 1);

  G256_OFFSETS();

  f32x4 acc[8][4];
  const f32x4 zero = {0.f, 0.f, 0.f, 0.f};
#pragma unroll
  for (int i = 0; i < 8; ++i)
#pragma unroll
    for (int j = 0; j < 4; ++j) acc[i][j] = zero;

  bf16x8 Ar[8][2], Br[2][2];

  G256_KLOOP(E256_STAGE, 32);  // K = FDIM = 2048 -> 32 tiles

  // epilogue: relu(acc + bias) -> bf16 slot rows (contiguous, never gathered)
  const int orow = slotBase[e] + rowStart;
#pragma unroll
  for (int i = 0; i < 8; ++i) {
#pragma unroll
    for (int r = 0; r < 4; ++r) {
      const int row = orow + wm + i * 16 + lhi * 4 + r;
#pragma unroll
      for (int j = 0; j < 4; ++j) {
        const int col = nBase + wn + j * 16 + llo;
        const float v = fmaxf(acc[i][j][r] + eb[e * UDIM + col], 0.f);
        eout[(size_t)row * UDIM + col] = (bf16)v;
      }
    }
  }
}

// ---------- combine: moeb[tok] = g0*eout[p0] + g1*eout[p1] ----------
__global__ __launch_bounds__(256) void moe_combine(
    const bf16* __restrict__ eout, const int* __restrict__ pidx,
    const float* __restrict__ tgate, const int* __restrict__ slotBase,
    bf16* __restrict__ moeb)
{
  const int tok = blockIdx.x;
  const int p0 = pidx[2 * tok], p1 = pidx[2 * tok + 1];
  const int r0 = slotBase[p0 >> 14] + (p0 & 16383);
  const int r1 = slotBase[p1 >> 14] + (p1 & 16383);
  const float g0 = tgate[2 * tok], g1 = tgate[2 * tok + 1];
  const int cb = threadIdx.x * 8;
  bf16x8 a = *(const bf16x8*)(eout + (size_t)r0 * UDIM + cb);
  bf16x8 b = *(const bf16x8*)(eout + (size_t)r1 * UDIM + cb);
  bf16x8 o;
#pragma unroll
  for (int u = 0; u < 8; ++u)
    o[u] = (bf16)(g0 * (float)a[u] + g1 * (float)b[u]);
  *(bf16x8*)(moeb + (size_t)tok * UDIM + cb) = o;
}

// ---------- transpose fp32 [R][C] -> bf16 [C][R], 64x64 tiles ----------
__global__ __launch_bounds__(256) void transpose_kernel(
    const float* __restrict__ in, bf16* __restrict__ out,
    int R, int C, long long inZ, long long outZ)
{
  __shared__ float tile[64][65];
  const long long zi = (long long)blockIdx.z * inZ;
  const long long zo = (long long)blockIdx.z * outZ;
  const int r0 = blockIdx.y * 64, c0 = blockIdx.x * 64;
  const int tid = threadIdx.x;
  const int tr = tid >> 4;
  const int tc = (tid & 15) * 4;
#pragma unroll
  for (int it = 0; it < 4; ++it) {
    int r = it * 16 + tr;
    float4 v = *(const float4*)(in + zi + (size_t)(r0 + r) * C + c0 + tc);
    tile[r][tc] = v.x; tile[r][tc + 1] = v.y; tile[r][tc + 2] = v.z; tile[r][tc + 3] = v.w;
  }
  __syncthreads();
#pragma unroll
  for (int it = 0; it < 4; ++it) {
    int c = it * 16 + tr;
    bf16x4 ov;
    ov[0] = (bf16)tile[tc + 0][c];
    ov[1] = (bf16)tile[tc + 1][c];
    ov[2] = (bf16)tile[tc + 2][c];
    ov[3] = (bf16)tile[tc + 3][c];
    *(bf16x4*)(out + zo + (size_t)(c0 + c) * R + r0 + tc) = ov;
  }
}

__global__ __launch_bounds__(256) void concat_bias(
    const float* __restrict__ bq, const float* __restrict__ bk,
    const float* __restrict__ bv, float* __restrict__ out)
{
  int i = blockIdx.x * 256 + threadIdx.x;
  if (i < 2048) out[i] = bq[i];
  else if (i < 4096) out[i] = bk[i - 2048];
  else if (i < 6144) out[i] = bv[i - 4096];
}

// ---------- router: logits, softmax, top-2, bucket scatter; fuses x->bf16 ----------
__global__ __launch_bounds__(256) void router_kernel(
    const float* __restrict__ x, const float* __restrict__ rw,
    const float* __restrict__ rb, bf16* __restrict__ xb,
    int* __restrict__ cnt, int* __restrict__ btok,
    int* __restrict__ pidx, float* __restrict__ tgate)
{
  const int tid = threadIdx.x, lane = tid & 63, wave = tid >> 6;
  const int tokBase = blockIdx.x * 16 + wave * 4;
  float acc[4][16];
#pragma unroll
  for (int t = 0; t < 4; ++t)
#pragma unroll
    for (int e = 0; e < 16; ++e) acc[t][e] = 0.f;

#pragma unroll 1
  for (int c = 0; c < 8; ++c) {
    const int f = c * 256 + lane * 4;
    float xv[4][4];
#pragma unroll
    for (int t = 0; t < 4; ++t) {
      float4 v = *(const float4*)(x + (size_t)(tokBase + t) * FDIM + f);
      xv[t][0] = v.x; xv[t][1] = v.y; xv[t][2] = v.z; xv[t][3] = v.w;
      bf16x4 b; b[0] = (bf16)v.x; b[1] = (bf16)v.y; b[2] = (bf16)v.z; b[3] = (bf16)v.w;
      *(bf16x4*)(xb + (size_t)(tokBase + t) * FDIM + f) = b;
    }
#pragma unroll
    for (int ff = 0; ff < 4; ++ff) {
      const float* rwr = rw + (size_t)(f + ff) * 16;
      float4 r0 = *(const float4*)(rwr);
      float4 r1 = *(const float4*)(rwr + 4);
      float4 r2 = *(const float4*)(rwr + 8);
      float4 r3 = *(const float4*)(rwr + 12);
      float rr[16] = {r0.x, r0.y, r0.z, r0.w, r1.x, r1.y, r1.z, r1.w,
                      r2.x, r2.y, r2.z, r2.w, r3.x, r3.y, r3.z, r3.w};
#pragma unroll
      for (int t = 0; t < 4; ++t) {
        float xs = xv[t][ff];
#pragma unroll
        for (int e = 0; e < 16; ++e) acc[t][e] = fmaf(xs, rr[e], acc[t][e]);
      }
    }
  }
#pragma unroll
  for (int t = 0; t < 4; ++t)
#pragma unroll
    for (int e = 0; e < 16; ++e) {
      float v = acc[t][e];
      v += __shfl_xor(v, 32); v += __shfl_xor(v, 16); v += __shfl_xor(v, 8);
      v += __shfl_xor(v, 4);  v += __shfl_xor(v, 2);  v += __shfl_xor(v, 1);
      acc[t][e] = v;
    }
  if (lane < 4) {
    const int tok = tokBase + lane;
    float lg[16];
#pragma unroll
    for (int e = 0; e < 16; ++e) lg[e] = acc[lane][e] + rb[e];
    float mx = lg[0];
#pragma unroll
    for (int e = 1; e < 16; ++e) mx = fmaxf(mx, lg[e]);
    float p[16], s = 0.f;
#pragma unroll
    for (int e = 0; e < 16; ++e) { p[e] = __expf(lg[e] - mx); s += p[e]; }
    const float inv = 1.f / s;
    int e0 = 0;
#pragma unroll
    for (int e = 1; e < 16; ++e) if (lg[e] > lg[e0]) e0 = e;
    int e1 = (e0 == 0) ? 1 : 0;
#pragma unroll
    for (int e = 0; e < 16; ++e) { if (e != e0 && lg[e] > lg[e1]) e1 = e; }
    const float g0 = p[e0] * inv, g1 = p[e1] * inv;
    int s0 = atomicAdd(cnt + e0, 1);
    btok[e0 * BSTRIDE + s0] = tok;
    pidx[2 * tok]     = (e0 << 14) | s0;
    tgate[2 * tok]    = g0;
    int s1 = atomicAdd(cnt + e1, 1);
    btok[e1 * BSTRIDE + s1] = tok;
    pidx[2 * tok + 1] = (e1 << 14) | s1;
    tgate[2 * tok + 1] = g1;
  }
}

// ---------- pad buckets to x256, build tile map + slot bases + pass bounds ----------
__global__ void finalize_buckets(const int* __restrict__ cnt, int* __restrict__ btok,
                                 int2* __restrict__ tmap, int* __restrict__ ntl3,
                                 int* __restrict__ slotBase)
{
  __shared__ int tilesS[16];
  const int tid = threadIdx.x;
  if (tid < 16) tilesS[tid] = (cnt[tid] + 255) >> 8;
  __syncthreads();
  for (int e = 0; e < 16; ++e) {
    int c = cnt[e], end = tilesS[e] << 8;
    for (int i = c + tid; i < end; i += 256) btok[e * BSTRIDE + i] = 0;
  }
  if (tid == 0) {
    int s = 0, sA = 0, sb = 0;
    for (int e = 0; e < 16; ++e) {
      slotBase[e] = sb;
      for (int m = 0; m < tilesS[e]; ++m) { tmap[s] = make_int2(e, m << 8); ++s; }
      sb += tilesS[e] << 8;
      if (e == 7) sA = s;
    }
    ntl3[0] = 0; ntl3[1] = sA; ntl3[2] = s;
  }
}

// ---------- per-token MLA: scores, softmax over 16 heads, attn*v ----------
__global__ __launch_bounds__(256) void attn_kernel(
    const bf16* __restrict__ qkv, bf16* __restrict__ aout)
{
  const int lane = threadIdx.x & 63, wave = threadIdx.x >> 6;
  const int tok = blockIdx.x * 4 + wave;
  const bf16* base = qkv + (size_t)tok * (3 * DMODEL);
  const int h = lane >> 2, part = lane & 3;
  const int off = h * 128 + part * 32;
  float dot = 0.f;
#pragma unroll
  for (int c = 0; c < 4; ++c) {
    bf16x8 qv = *(const bf16x8*)(base + off + c * 8);
    bf16x8 kv = *(const bf16x8*)(base + DMODEL + off + c * 8);
#pragma unroll
    for (int u = 0; u < 8; ++u) dot += (float)qv[u] * (float)kv[u];
  }
  dot += __shfl_xor(dot, 1);
  dot += __shfl_xor(dot, 2);
  const float score = dot * 0.08838834764831845f;  // 1/sqrt(128)
  float sc[16];
#pragma unroll
  for (int e = 0; e < 16; ++e) sc[e] = __shfl(score, e * 4);
  float mx = sc[0];
#pragma unroll
  for (int e = 1; e < 16; ++e) mx = fmaxf(mx, sc[e]);
  float sum = 0.f, mex = 0.f;
#pragma unroll
  for (int e = 0; e < 16; ++e) {
    float ex = __expf(sc[e] - mx);
    sum += ex;
    mex = (e == h) ? ex : mex;
  }
  const float attn = mex / sum;
  bf16* op = aout + (size_t)tok * DMODEL + off;
#pragma unroll
  for (int c = 0; c < 4; ++c) {
    bf16x8 vv = *(const bf16x8*)(base + 2 * DMODEL + off + c * 8);
    bf16x8 ov;
#pragma unroll
    for (int u = 0; u < 8; ++u) ov[u] = (bf16)(attn * (float)vv[u]);
    *(bf16x8*)(op + c * 8) = ov;
  }
}

extern "C" void kernel_launch(void* const* d_in, const int* in_sizes, int n_in,
                              void* d_out, int out_size, void* d_ws, size_t ws_size,
                              hipStream_t stream) {
  const float* x   = (const float*)d_in[0];
  const float* rw  = (const float*)d_in[1];
  const float* rb  = (const float*)d_in[2];
  const float* ew  = (const float*)d_in[3];
  const float* eb  = (const float*)d_in[4];
  const float* wq  = (const float*)d_in[5];
  const float* bq  = (const float*)d_in[6];
  const float* wk  = (const float*)d_in[7];
  const float* bk  = (const float*)d_in[8];
  const float* wv  = (const float*)d_in[9];
  const float* bv  = (const float*)d_in[10];
  const float* wo_ = (const float*)d_in[11];
  const float* bo  = (const float*)d_in[12];
  float* out = (float*)d_out;

  // Allow 128 KiB dynamic LDS for the 256^2 8-phase GEMMs.
  static bool attrSet = false;
  if (!attrSet) {
    hipFuncSetAttribute((const void*)gemm256<bf16>,
                        hipFuncAttributeMaxDynamicSharedMemorySize, 131072);
    hipFuncSetAttribute((const void*)gemm256<float>,
                        hipFuncAttributeMaxDynamicSharedMemorySize, 131072);
    hipFuncSetAttribute((const void*)expert_gemm256,
                        hipFuncAttributeMaxDynamicSharedMemorySize, 131072);
    attrSet = true;
  }

  uint8_t* ws = (uint8_t*)d_ws;
  // Static overlapped layout, peak ~181 MiB:
  //  [0,64M):    ewt half (experts e0..e0+7)  ->  moeb [0,32M)  ->  aout [0,32M)
  //  [64M,160M): eout [64M,~148M)             ->  qkv  [64M,160M)
  //  [160M,192M):xb                           ->  qkvt [160M,184M) + wot [184M,192M)
  //  [192M,...): misc (bqkv, cnt, ntl3, slotBase, tmap, btok, pidx, tgate)
  bf16*  ewt   = (bf16*)(ws);
  bf16*  moeb  = (bf16*)(ws);
  bf16*  aout  = (bf16*)(ws);
  bf16*  eout  = (bf16*)(ws + 67108864);
  bf16*  qkv   = (bf16*)(ws + 67108864);
  bf16*  xb    = (bf16*)(ws + 167772160);
  bf16*  qkvt  = (bf16*)(ws + 167772160);
  bf16*  wot   = (bf16*)(ws + 167772160 + 25165824);
  uint8_t* misc = ws + 201326592;
  float* bqkv  = (float*)(misc);            misc += 24576;
  int*   cnt   = (int*)(misc);              misc += 256;
  int*   ntl3  = (int*)(misc);              misc += 256;
  int*   slotBase = (int*)(misc);           misc += 256;
  int2*  tmap  = (int2*)(misc);             misc += 2048;
  int*   btok  = (int*)(misc);              misc += 540672;
  int*   pidx  = (int*)(misc);              misc += 65536;
  float* tgate = (float*)(misc);            misc += 65536;

  hipMemsetAsync(cnt, 0, 64, stream);

  // experts 0..7 -> ewt (bf16, [e][U][F])
  transpose_kernel<<<dim3(32, 32, 8), 256, 0, stream>>>(ew, ewt, FDIM, UDIM, 4194304LL, 4194304LL);
  router_kernel<<<512, 256, 0, stream>>>(x, rw, rb, xb, cnt, btok, pidx, tgate);
  finalize_buckets<<<1, 256, 0, stream>>>(cnt, btok, tmap, ntl3, slotBase);
  expert_gemm256<<<dim3(8, 72), 512, 131072, stream>>>(xb, ewt, eb, btok, tmap, ntl3, slotBase, 0, 0, eout);
  // experts 8..15 into the same 64MB buffer
  transpose_kernel<<<dim3(32, 32, 8), 256, 0, stream>>>(ew + (size_t)8 * 4194304, ewt, FDIM, UDIM, 4194304LL, 4194304LL);
  expert_gemm256<<<dim3(8, 72), 512, 131072, stream>>>(xb, ewt, eb, btok, tmap, ntl3, slotBase, 1, 8, eout);

  // combine top-2 slots -> moeb (ewt dead; moeb at ws+0)
  moe_combine<<<8192, 256, 0, stream>>>(eout, pidx, tgate, slotBase, moeb);

  // xb dead now: transpose qkv/wo weights into its region
  transpose_kernel<<<dim3(32, 32, 1), 256, 0, stream>>>(wq, qkvt,            UDIM, DMODEL, 0, 0);
  transpose_kernel<<<dim3(32, 32, 1), 256, 0, stream>>>(wk, qkvt + 4194304,  UDIM, DMODEL, 0, 0);
  transpose_kernel<<<dim3(32, 32, 1), 256, 0, stream>>>(wv, qkvt + 8388608,  UDIM, DMODEL, 0, 0);
  transpose_kernel<<<dim3(32, 32, 1), 256, 0, stream>>>(wo_, wot, DMODEL, DMODEL, 0, 0);
  concat_bias<<<24, 256, 0, stream>>>(bq, bk, bv, bqkv);

  // fused QKV GEMM: [8192 x 6144 x 2048] (eout dead; qkv at ws+64M)
  gemm256<bf16><<<dim3(768), 512, 131072, stream>>>(moeb, qkvt, bqkv, qkv, BTOK, 3 * DMODEL, UDIM);
  attn_kernel<<<2048, 256, 0, stream>>>(qkv, aout);
  // output projection: [8192 x 2048 x 2048] + bo -> fp32 d_out (256 blocks)
  gemm256<float><<<dim3(256), 512, 131072, stream>>>(aout, wot, bo, out, BTOK, DMODEL, 2048);
}

// Round 3
// 1068.970 us; speedup vs baseline: 1.2784x; 1.0488x over previous
//
#include <hip/hip_runtime.h>
#include <hip/hip_bf16.h>
#include <cstdint>

typedef __bf16 bf16;
typedef __bf16 bf16x4 __attribute__((ext_vector_type(4)));
typedef __bf16 bf16x8 __attribute__((ext_vector_type(8)));
typedef float  f32x4  __attribute__((ext_vector_type(4)));

#define BTOK 8192
#define FDIM 2048
#define NEXP 16
#define UDIM 2048
#define DMODEL 2048
#define BSTRIDE 8448  // bucket capacity per expert (8192 + 256 pad), multiple of 256

__device__ __forceinline__ void gl2lds16(const void* g, void* l) {
  __builtin_amdgcn_global_load_lds(
      (const __attribute__((address_space(1))) void*)g,
      (__attribute__((address_space(3))) void*)l, 16, 0, 0);
}

// ================= 256x256 8-phase GEMM core (T1+T2+T3/T4+T5) =================
// BM=BN=256, BK=64, 512 threads (8 waves as 2Mx4N), per-wave C = 128x64.
// LDS 128 KiB: 2 buffers x { A: [ks=2][256 rows][32 cols], B: same } bf16,
// st_16x32 swizzle (chunk ^= ((row>>3)&1)<<1) applied via pre-swizzled
// global source (linear global_load_lds dest) + swizzled ds_read addrs.
// Per K-tile: 4 phases {ds_read subtile | stage 1 half-tile -> barrier ->
// lgkmcnt(0) -> setprio(1) -> 16 MFMA -> setprio(0) -> barrier}.
// Counted vmcnt(4) once per K-tile; drain only at the end.

#define G256_BAR()  __builtin_amdgcn_s_barrier()
#define G256_LGK0() asm volatile("s_waitcnt lgkmcnt(0)" ::: "memory")

#define G256_STAGE(h, kt) do {                                               \
    const bf16* sb_ = ((h) < 2) ? Ab : Bb;                                   \
    const int ro_ = (((kt) & 1) << 16) + (((h) >= 2) ? 32768 : 0)            \
                    + (((h) & 1) << 13);                                     \
    _Pragma("unroll")                                                        \
    for (int l_ = 0; l_ < 2; ++l_) {                                         \
      const int u_   = (((h) & 1) << 9) + (l_ << 10) + tid;                  \
      const int row_ = (u_ & 1023) >> 2;                                     \
      const int ch_  = ((u_ >> 10) << 2)                                     \
                       + ((u_ & 3) ^ (((row_ >> 3) & 1) << 1));              \
      const bf16* s_ = sb_ + (size_t)(row_ * Kdim + (kt) * 64 + ch_ * 8);    \
      char* d_ = smem + ro_ + (l_ << 14) + ((tid & ~63) << 4);               \
      gl2lds16(s_, d_);                                                      \
    }                                                                        \
  } while (0)

// expert variant: per-thread gathered row base pointers (aRow0/aRow1 for A
// halves, bRow0/bRow1 for B halves), same LDS layout/swizzle as G256_STAGE.
#define E256_STAGE(h, kt) do {                                               \
    const bf16* rp_ = ((h) == 0) ? aRow0 : ((h) == 1) ? aRow1                \
                      : ((h) == 2) ? bRow0 : bRow1;                          \
    const int ro_ = (((kt) & 1) << 16) + (((h) >= 2) ? 32768 : 0)            \
                    + (((h) & 1) << 13);                                     \
    _Pragma("unroll")                                                        \
    for (int l_ = 0; l_ < 2; ++l_) {                                         \
      const bf16* s_ = rp_ + (kt) * 64 + (l_ * 4 + chsw) * 8;                \
      char* d_ = smem + ro_ + (l_ << 14) + ((tid & ~63) << 4);               \
      gl2lds16(s_, d_);                                                      \
    }                                                                        \
  } while (0)

#define G256_LDA(I0)                                                         \
  _Pragma("unroll") for (int i_ = 0; i_ < 4; ++i_)                           \
  _Pragma("unroll") for (int ks_ = 0; ks_ < 2; ++ks_)                        \
    Ar[(I0) + i_][ks_] =                                                     \
        *(const bf16x8*)(smem + c + aOff[(I0) + i_] + ks_ * 16384);

#define G256_LDB(J0)                                                         \
  _Pragma("unroll") for (int jj_ = 0; jj_ < 2; ++jj_)                        \
  _Pragma("unroll") for (int ks_ = 0; ks_ < 2; ++ks_)                        \
    Br[jj_][ks_] =                                                           \
        *(const bf16x8*)(smem + c + bOff[(J0) + jj_] + ks_ * 16384);

#define G256_MFMA16(I0, J0)                                                  \
  _Pragma("unroll") for (int i_ = 0; i_ < 4; ++i_)                           \
  _Pragma("unroll") for (int jj_ = 0; jj_ < 2; ++jj_)                        \
  _Pragma("unroll") for (int ks_ = 0; ks_ < 2; ++ks_)                        \
    acc[(I0) + i_][(J0) + jj_] = __builtin_amdgcn_mfma_f32_16x16x32_bf16(    \
        Ar[(I0) + i_][ks_], Br[jj_][ks_], acc[(I0) + i_][(J0) + jj_], 0, 0, 0);

// K-loop phases shared by both 256^2 kernels (STAGE_M = staging macro).
#define G256_OFFSETS()                                                       \
  int aOff[8], bOff[4];                                                      \
  _Pragma("unroll")                                                          \
  for (int i = 0; i < 8; ++i) {                                              \
    const int row = wm + i * 16 + llo;                                       \
    aOff[i] = (row * 64 + lhi * 16) ^ (((row >> 3) & 1) << 5);               \
  }                                                                          \
  _Pragma("unroll")                                                          \
  for (int j = 0; j < 4; ++j) {                                              \
    const int row = wn + j * 16 + llo;                                       \
    bOff[j] = 32768 + ((row * 64 + lhi * 16) ^ (((row >> 3) & 1) << 5));     \
  }

#define G256_KLOOP(STAGE_M, NT)                                              \
  STAGE_M(0, 0); STAGE_M(1, 0); STAGE_M(2, 0); STAGE_M(3, 0);                \
  STAGE_M(0, 1); STAGE_M(1, 1);                                              \
  asm volatile("s_waitcnt vmcnt(4)" ::: "memory");                           \
  G256_BAR();                                                                \
  _Pragma("unroll 1")                                                        \
  for (int t = 0; t < (NT); ++t) {                                           \
    const int c = (t & 1) << 16;                                             \
    const bool p1 = (t + 1 < (NT)), p2 = (t + 2 < (NT));                     \
    G256_LDA(0); G256_LDB(0);                                                \
    if (p1) STAGE_M(2, t + 1);                                               \
    G256_BAR(); G256_LGK0();                                                 \
    __builtin_amdgcn_s_setprio(1); G256_MFMA16(0, 0); __builtin_amdgcn_s_setprio(0); \
    G256_BAR();                                                              \
    G256_LDA(4);                                                             \
    if (p1) STAGE_M(3, t + 1);                                               \
    G256_BAR(); G256_LGK0();                                                 \
    __builtin_amdgcn_s_setprio(1); G256_MFMA16(4, 0); __builtin_amdgcn_s_setprio(0); \
    G256_BAR();                                                              \
    G256_LDB(2);                                                             \
    if (p2) STAGE_M(0, t + 2);                                               \
    G256_BAR(); G256_LGK0();                                                 \
    __builtin_amdgcn_s_setprio(1); G256_MFMA16(4, 2); __builtin_amdgcn_s_setprio(0); \
    G256_BAR();                                                              \
    if (p2) STAGE_M(1, t + 2);                                               \
    G256_BAR();                                                              \
    __builtin_amdgcn_s_setprio(1); G256_MFMA16(0, 2); __builtin_amdgcn_s_setprio(0); \
    if (p2) { asm volatile("s_waitcnt vmcnt(4)" ::: "memory"); }             \
    else    { asm volatile("s_waitcnt vmcnt(0)" ::: "memory"); }             \
    G256_BAR();                                                              \
  }

template <typename OutT>
__global__ __launch_bounds__(512, 2) void gemm256(
    const bf16* __restrict__ A, const bf16* __restrict__ Bt,
    const float* __restrict__ bias, OutT* __restrict__ C,
    int M, int N, int Kdim)
{
  extern __shared__ __align__(16) char smem[];  // 131072 bytes
  const int tid  = threadIdx.x;
  const int lane = tid & 63;
  const int wave = tid >> 6;
  const int wm   = (wave >> 2) << 7;   // 0 / 128
  const int wn   = (wave & 3) << 6;    // 0 / 64 / 128 / 192
  const int lhi  = lane >> 4, llo = lane & 15;

  // T1: bijective XCD swizzle on 1-D grid (nwg % 8 == 0 for both call sites)
  const int nbx = N >> 8;
  const int nwg = (M >> 8) * nbx;
  const int q8  = nwg >> 3;
  const int bid = (int)blockIdx.x;
  const int swz = (bid & 7) * q8 + (bid >> 3);
  const int mBase = (swz / nbx) << 8;
  const int nBase = (swz % nbx) << 8;

  const bf16* Ab = A + (size_t)mBase * Kdim;
  const bf16* Bb = Bt + (size_t)nBase * Kdim;
  const int NT = Kdim >> 6;

  G256_OFFSETS();

  f32x4 acc[8][4];
  const f32x4 zero = {0.f, 0.f, 0.f, 0.f};
#pragma unroll
  for (int i = 0; i < 8; ++i)
#pragma unroll
    for (int j = 0; j < 4; ++j) acc[i][j] = zero;

  bf16x8 Ar[8][2], Br[2][2];

  G256_KLOOP(G256_STAGE, NT);

  // epilogue: C = acc + bias
#pragma unroll
  for (int i = 0; i < 8; ++i) {
#pragma unroll
    for (int r = 0; r < 4; ++r) {
      const int row = mBase + wm + i * 16 + lhi * 4 + r;
#pragma unroll
      for (int j = 0; j < 4; ++j) {
        const int col = nBase + wn + j * 16 + llo;
        C[(size_t)row * N + col] = (OutT)(acc[i][j][r] + bias[col]);
      }
    }
  }
}

// ---------- expert GEMM, 256^2 8-phase, gathered A rows, bf16 slot output ----------
// eout[slot][2048] = relu(x[tok(slot)] @ We + be)   (no gate, no atomics)
// Tile range [ntl[pa], ntl[pb]); expert weight base = ewt + (e - e0glob)*2048*2048.
__global__ __launch_bounds__(512, 2) void expert_gemm256(
    const bf16* __restrict__ xb, const bf16* __restrict__ ewt,
    const float* __restrict__ eb, const int* __restrict__ btok,
    const int2* __restrict__ tmap, const int* __restrict__ ntl,
    const int* __restrict__ slotBase, int pa, int pb, int e0glob,
    bf16* __restrict__ eout)
{
  extern __shared__ __align__(16) char smem[];  // 131072 bytes
  const int tstart = ntl[pa], tend = ntl[pb];
  const int t = tstart + (int)blockIdx.y;
  if (t >= tend) return;
  const int2 mp = tmap[t];
  const int e = mp.x, rowStart = mp.y;
  const int nBase = (int)blockIdx.x << 8;
  const int tid  = threadIdx.x;
  const int lane = tid & 63;
  const int wave = tid >> 6;
  const int wm   = (wave >> 2) << 7;
  const int wn   = (wave & 3) << 6;
  const int lhi  = lane >> 4, llo = lane & 15;

  const int r0 = tid >> 2;
  const int bbase = e * BSTRIDE + rowStart;
  // per-thread gathered source rows (A halves) + weight rows (B halves)
  const bf16* aRow0 = xb + (size_t)btok[bbase + r0] * FDIM;
  const bf16* aRow1 = xb + (size_t)btok[bbase + 128 + r0] * FDIM;
  const bf16* Bb = ewt + ((size_t)(e - e0glob) << 22);
  const bf16* bRow0 = Bb + (size_t)(nBase + r0) * FDIM;
  const bf16* bRow1 = Bb + (size_t)(nBase + 128 + r0) * FDIM;
  // swizzled 16B-chunk index (same parity for row and row+128)
  const int chsw = (tid & 3) ^ (((r0 >> 3) & 1) << 1);

  G256_OFFSETS();

  f32x4 acc[8][4];
  const f32x4 zero = {0.f, 0.f, 0.f, 0.f};
#pragma unroll
  for (int i = 0; i < 8; ++i)
#pragma unroll
    for (int j = 0; j < 4; ++j) acc[i][j] = zero;

  bf16x8 Ar[8][2], Br[2][2];

  G256_KLOOP(E256_STAGE, 32);  // K = FDIM = 2048 -> 32 tiles

  // epilogue: relu(acc + bias) -> bf16 slot rows (contiguous, never gathered)
  const int orow = slotBase[e] + rowStart;
#pragma unroll
  for (int i = 0; i < 8; ++i) {
#pragma unroll
    for (int r = 0; r < 4; ++r) {
      const int row = orow + wm + i * 16 + lhi * 4 + r;
#pragma unroll
      for (int j = 0; j < 4; ++j) {
        const int col = nBase + wn + j * 16 + llo;
        const float v = fmaxf(acc[i][j][r] + eb[e * UDIM + col], 0.f);
        eout[(size_t)row * UDIM + col] = (bf16)v;
      }
    }
  }
}

// ---------- combine: moeb[tok] = g0*eout[p0] + g1*eout[p1] ----------
__global__ __launch_bounds__(256) void moe_combine(
    const bf16* __restrict__ eout, const int* __restrict__ pidx,
    const float* __restrict__ tgate, const int* __restrict__ slotBase,
    bf16* __restrict__ moeb)
{
  const int tok = blockIdx.x;
  const int p0 = pidx[2 * tok], p1 = pidx[2 * tok + 1];
  const int r0 = slotBase[p0 >> 14] + (p0 & 16383);
  const int r1 = slotBase[p1 >> 14] + (p1 & 16383);
  const float g0 = tgate[2 * tok], g1 = tgate[2 * tok + 1];
  const int cb = threadIdx.x * 8;
  bf16x8 a = *(const bf16x8*)(eout + (size_t)r0 * UDIM + cb);
  bf16x8 b = *(const bf16x8*)(eout + (size_t)r1 * UDIM + cb);
  bf16x8 o;
#pragma unroll
  for (int u = 0; u < 8; ++u)
    o[u] = (bf16)(g0 * (float)a[u] + g1 * (float)b[u]);
  *(bf16x8*)(moeb + (size_t)tok * UDIM + cb) = o;
}

// ---------- transpose fp32 [R][C] -> bf16 [C][R], 64x64 tiles ----------
__global__ __launch_bounds__(256) void transpose_kernel(
    const float* __restrict__ in, bf16* __restrict__ out,
    int R, int C, long long inZ, long long outZ)
{
  __shared__ float tile[64][65];
  const long long zi = (long long)blockIdx.z * inZ;
  const long long zo = (long long)blockIdx.z * outZ;
  const int r0 = blockIdx.y * 64, c0 = blockIdx.x * 64;
  const int tid = threadIdx.x;
  const int tr = tid >> 4;
  const int tc = (tid & 15) * 4;
#pragma unroll
  for (int it = 0; it < 4; ++it) {
    int r = it * 16 + tr;
    float4 v = *(const float4*)(in + zi + (size_t)(r0 + r) * C + c0 + tc);
    tile[r][tc] = v.x; tile[r][tc + 1] = v.y; tile[r][tc + 2] = v.z; tile[r][tc + 3] = v.w;
  }
  __syncthreads();
#pragma unroll
  for (int it = 0; it < 4; ++it) {
    int c = it * 16 + tr;
    bf16x4 ov;
    ov[0] = (bf16)tile[tc + 0][c];
    ov[1] = (bf16)tile[tc + 1][c];
    ov[2] = (bf16)tile[tc + 2][c];
    ov[3] = (bf16)tile[tc + 3][c];
    *(bf16x4*)(out + zo + (size_t)(c0 + c) * R + r0 + tc) = ov;
  }
}

__global__ __launch_bounds__(256) void concat_bias(
    const float* __restrict__ bq, const float* __restrict__ bk,
    const float* __restrict__ bv, float* __restrict__ out)
{
  int i = blockIdx.x * 256 + threadIdx.x;
  if (i < 2048) out[i] = bq[i];
  else if (i < 4096) out[i] = bk[i - 2048];
  else if (i < 6144) out[i] = bv[i - 4096];
}

// ---------- router: logits, softmax, top-2, bucket scatter; fuses x->bf16 ----------
__global__ __launch_bounds__(256) void router_kernel(
    const float* __restrict__ x, const float* __restrict__ rw,
    const float* __restrict__ rb, bf16* __restrict__ xb,
    int* __restrict__ cnt, int* __restrict__ btok,
    int* __restrict__ pidx, float* __restrict__ tgate)
{
  const int tid = threadIdx.x, lane = tid & 63, wave = tid >> 6;
  const int tokBase = blockIdx.x * 16 + wave * 4;
  float acc[4][16];
#pragma unroll
  for (int t = 0; t < 4; ++t)
#pragma unroll
    for (int e = 0; e < 16; ++e) acc[t][e] = 0.f;

#pragma unroll 1
  for (int c = 0; c < 8; ++c) {
    const int f = c * 256 + lane * 4;
    float xv[4][4];
#pragma unroll
    for (int t = 0; t < 4; ++t) {
      float4 v = *(const float4*)(x + (size_t)(tokBase + t) * FDIM + f);
      xv[t][0] = v.x; xv[t][1] = v.y; xv[t][2] = v.z; xv[t][3] = v.w;
      bf16x4 b; b[0] = (bf16)v.x; b[1] = (bf16)v.y; b[2] = (bf16)v.z; b[3] = (bf16)v.w;
      *(bf16x4*)(xb + (size_t)(tokBase + t) * FDIM + f) = b;
    }
#pragma unroll
    for (int ff = 0; ff < 4; ++ff) {
      const float* rwr = rw + (size_t)(f + ff) * 16;
      float4 r0 = *(const float4*)(rwr);
      float4 r1 = *(const float4*)(rwr + 4);
      float4 r2 = *(const float4*)(rwr + 8);
      float4 r3 = *(const float4*)(rwr + 12);
      float rr[16] = {r0.x, r0.y, r0.z, r0.w, r1.x, r1.y, r1.z, r1.w,
                      r2.x, r2.y, r2.z, r2.w, r3.x, r3.y, r3.z, r3.w};
#pragma unroll
      for (int t = 0; t < 4; ++t) {
        float xs = xv[t][ff];
#pragma unroll
        for (int e = 0; e < 16; ++e) acc[t][e] = fmaf(xs, rr[e], acc[t][e]);
      }
    }
  }
#pragma unroll
  for (int t = 0; t < 4; ++t)
#pragma unroll
    for (int e = 0; e < 16; ++e) {
      float v = acc[t][e];
      v += __shfl_xor(v, 32); v += __shfl_xor(v, 16); v += __shfl_xor(v, 8);
      v += __shfl_xor(v, 4);  v += __shfl_xor(v, 2);  v += __shfl_xor(v, 1);
      acc[t][e] = v;
    }
  if (lane < 4) {
    const int tok = tokBase + lane;
    float lg[16];
#pragma unroll
    for (int e = 0; e < 16; ++e) lg[e] = acc[lane][e] + rb[e];
    float mx = lg[0];
#pragma unroll
    for (int e = 1; e < 16; ++e) mx = fmaxf(mx, lg[e]);
    float p[16], s = 0.f;
#pragma unroll
    for (int e = 0; e < 16; ++e) { p[e] = __expf(lg[e] - mx); s += p[e]; }
    const float inv = 1.f / s;
    int e0 = 0;
#pragma unroll
    for (int e = 1; e < 16; ++e) if (lg[e] > lg[e0]) e0 = e;
    int e1 = (e0 == 0) ? 1 : 0;
#pragma unroll
    for (int e = 0; e < 16; ++e) { if (e != e0 && lg[e] > lg[e1]) e1 = e; }
    const float g0 = p[e0] * inv, g1 = p[e1] * inv;
    int s0 = atomicAdd(cnt + e0, 1);
    btok[e0 * BSTRIDE + s0] = tok;
    pidx[2 * tok]     = (e0 << 14) | s0;
    tgate[2 * tok]    = g0;
    int s1 = atomicAdd(cnt + e1, 1);
    btok[e1 * BSTRIDE + s1] = tok;
    pidx[2 * tok + 1] = (e1 << 14) | s1;
    tgate[2 * tok + 1] = g1;
  }
}

// ---------- pad buckets to x256, build tile map + slot bases + pass bounds ----------
// ntl: [0, tiles(e0..5), tiles(e0..10), total]  (pass splits after e=5 and e=10)
__global__ void finalize_buckets(const int* __restrict__ cnt, int* __restrict__ btok,
                                 int2* __restrict__ tmap, int* __restrict__ ntl,
                                 int* __restrict__ slotBase)
{
  __shared__ int tilesS[16];
  const int tid = threadIdx.x;
  if (tid < 16) tilesS[tid] = (cnt[tid] + 255) >> 8;
  __syncthreads();
  for (int e = 0; e < 16; ++e) {
    int c = cnt[e], end = tilesS[e] << 8;
    for (int i = c + tid; i < end; i += 256) btok[e * BSTRIDE + i] = 0;
  }
  if (tid == 0) {
    int s = 0, s5 = 0, s10 = 0, sb = 0;
    for (int e = 0; e < 16; ++e) {
      slotBase[e] = sb;
      for (int m = 0; m < tilesS[e]; ++m) { tmap[s] = make_int2(e, m << 8); ++s; }
      sb += tilesS[e] << 8;
      if (e == 5) s5 = s;
      if (e == 10) s10 = s;
    }
    ntl[0] = 0; ntl[1] = s5; ntl[2] = s10; ntl[3] = s;
  }
}

// ---------- per-token MLA: scores, softmax over 16 heads, attn*v ----------
__global__ __launch_bounds__(256) void attn_kernel(
    const bf16* __restrict__ qkv, bf16* __restrict__ aout)
{
  const int lane = threadIdx.x & 63, wave = threadIdx.x >> 6;
  const int tok = blockIdx.x * 4 + wave;
  const bf16* base = qkv + (size_t)tok * (3 * DMODEL);
  const int h = lane >> 2, part = lane & 3;
  const int off = h * 128 + part * 32;
  float dot = 0.f;
#pragma unroll
  for (int c = 0; c < 4; ++c) {
    bf16x8 qv = *(const bf16x8*)(base + off + c * 8);
    bf16x8 kv = *(const bf16x8*)(base + DMODEL + off + c * 8);
#pragma unroll
    for (int u = 0; u < 8; ++u) dot += (float)qv[u] * (float)kv[u];
  }
  dot += __shfl_xor(dot, 1);
  dot += __shfl_xor(dot, 2);
  const float score = dot * 0.08838834764831845f;  // 1/sqrt(128)
  float sc[16];
#pragma unroll
  for (int e = 0; e < 16; ++e) sc[e] = __shfl(score, e * 4);
  float mx = sc[0];
#pragma unroll
  for (int e = 1; e < 16; ++e) mx = fmaxf(mx, sc[e]);
  float sum = 0.f, mex = 0.f;
#pragma unroll
  for (int e = 0; e < 16; ++e) {
    float ex = __expf(sc[e] - mx);
    sum += ex;
    mex = (e == h) ? ex : mex;
  }
  const float attn = mex / sum;
  bf16* op = aout + (size_t)tok * DMODEL + off;
#pragma unroll
  for (int c = 0; c < 4; ++c) {
    bf16x8 vv = *(const bf16x8*)(base + 2 * DMODEL + off + c * 8);
    bf16x8 ov;
#pragma unroll
    for (int u = 0; u < 8; ++u) ov[u] = (bf16)(attn * (float)vv[u]);
    *(bf16x8*)(op + c * 8) = ov;
  }
}

extern "C" void kernel_launch(void* const* d_in, const int* in_sizes, int n_in,
                              void* d_out, int out_size, void* d_ws, size_t ws_size,
                              hipStream_t stream) {
  const float* x   = (const float*)d_in[0];
  const float* rw  = (const float*)d_in[1];
  const float* rb  = (const float*)d_in[2];
  const float* ew  = (const float*)d_in[3];
  const float* eb  = (const float*)d_in[4];
  const float* wq  = (const float*)d_in[5];
  const float* bq  = (const float*)d_in[6];
  const float* wk  = (const float*)d_in[7];
  const float* bk  = (const float*)d_in[8];
  const float* wv  = (const float*)d_in[9];
  const float* bv  = (const float*)d_in[10];
  const float* wo_ = (const float*)d_in[11];
  const float* bo  = (const float*)d_in[12];
  float* out = (float*)d_out;

  // Allow 128 KiB dynamic LDS for the 256^2 8-phase GEMMs.
  static bool attrSet = false;
  if (!attrSet) {
    hipFuncSetAttribute((const void*)gemm256<bf16>,
                        hipFuncAttributeMaxDynamicSharedMemorySize, 131072);
    hipFuncSetAttribute((const void*)gemm256<float>,
                        hipFuncAttributeMaxDynamicSharedMemorySize, 131072);
    hipFuncSetAttribute((const void*)expert_gemm256,
                        hipFuncAttributeMaxDynamicSharedMemorySize, 131072);
    attrSet = true;
  }

  uint8_t* ws = (uint8_t*)d_ws;
  // Single-pass expert layout needs 128M (ewt16) + 80M (eout) + 32M (xb)
  // + ~0.7M misc = ~241.4 MiB.  Branch on ws_size; fallback = 3-pass within
  // the proven ~202 MiB footprint.
  const bool sp = (ws_size >= 253000000ULL);

  bf16 *ewt, *xb, *eout, *moeb, *qkvt, *wot, *qkv, *aout;
  uint8_t* misc;
  if (sp) {
    // Phase A (MoE): ewt16 [0,128M) + eout [128M,208M) + xb [208M,240M)
    // Phase B: moeb [0,32M) | qkvt [32M,56M) | wot [56M,64M) | aout [64M,96M)
    //          (all over dead ewt16)         | qkv [128M,224M) over dead eout/xb
    ewt  = (bf16*)(ws);
    eout = (bf16*)(ws + 134217728);
    xb   = (bf16*)(ws + 218103808);
    misc = ws + 251658240;
    moeb = (bf16*)(ws);
    qkvt = (bf16*)(ws + 33554432);
    wot  = (bf16*)(ws + 58720256);
    aout = (bf16*)(ws + 67108864);
    qkv  = (bf16*)(ws + 134217728);
  } else {
    // Proven overlapped layout (~202 MiB peak):
    //  [0,64M):    ewt (<=6 experts/pass) -> moeb [0,32M) -> aout [0,32M)
    //  [64M,160M): eout (<=84M)           -> qkv  [64M,160M)
    //  [160M,192M):xb                     -> qkvt [160M,184M) + wot [184M,192M)
    ewt  = (bf16*)(ws);
    moeb = (bf16*)(ws);
    aout = (bf16*)(ws);
    eout = (bf16*)(ws + 67108864);
    qkv  = (bf16*)(ws + 67108864);
    xb   = (bf16*)(ws + 167772160);
    qkvt = (bf16*)(ws + 167772160);
    wot  = (bf16*)(ws + 167772160 + 25165824);
    misc = ws + 201326592;
  }
  float* bqkv  = (float*)(misc);            misc += 24576;
  int*   cnt   = (int*)(misc);              misc += 256;
  int*   ntl   = (int*)(misc);              misc += 256;
  int*   slotBase = (int*)(misc);           misc += 256;
  int2*  tmap  = (int2*)(misc);             misc += 2048;
  int*   btok  = (int*)(misc);              misc += 540672;
  int*   pidx  = (int*)(misc);              misc += 65536;
  float* tgate = (float*)(misc);            misc += 65536;

  hipMemsetAsync(cnt, 0, 64, stream);

  router_kernel<<<512, 256, 0, stream>>>(x, rw, rb, xb, cnt, btok, pidx, tgate);
  finalize_buckets<<<1, 256, 0, stream>>>(cnt, btok, tmap, ntl, slotBase);

  if (sp) {
    // all 16 experts transposed upfront, ONE expert dispatch (~2 block-waves)
    transpose_kernel<<<dim3(32, 32, 16), 256, 0, stream>>>(ew, ewt, FDIM, UDIM, 4194304LL, 4194304LL);
    expert_gemm256<<<dim3(8, 80), 512, 131072, stream>>>(
        xb, ewt, eb, btok, tmap, ntl, slotBase, 0, 3, 0, eout);
  } else {
    // 3 static passes {0-5},{6-10},{11-15}: <=~220 active blocks per pass,
    // each fits one block-wave at 1 block/CU (kills the straggler wave).
    transpose_kernel<<<dim3(32, 32, 6), 256, 0, stream>>>(ew, ewt, FDIM, UDIM, 4194304LL, 4194304LL);
    expert_gemm256<<<dim3(8, 72), 512, 131072, stream>>>(
        xb, ewt, eb, btok, tmap, ntl, slotBase, 0, 1, 0, eout);
    transpose_kernel<<<dim3(32, 32, 5), 256, 0, stream>>>(ew + (size_t)6 * 4194304, ewt, FDIM, UDIM, 4194304LL, 4194304LL);
    expert_gemm256<<<dim3(8, 72), 512, 131072, stream>>>(
        xb, ewt, eb, btok, tmap, ntl, slotBase, 1, 2, 6, eout);
    transpose_kernel<<<dim3(32, 32, 5), 256, 0, stream>>>(ew + (size_t)11 * 4194304, ewt, FDIM, UDIM, 4194304LL, 4194304LL);
    expert_gemm256<<<dim3(8, 72), 512, 131072, stream>>>(
        xb, ewt, eb, btok, tmap, ntl, slotBase, 2, 3, 11, eout);
  }

  // combine top-2 slots -> moeb (ewt dead afterwards in both layouts)
  moe_combine<<<8192, 256, 0, stream>>>(eout, pidx, tgate, slotBase, moeb);

  // transpose qkv/wo weights (regions dead in both layouts by now)
  transpose_kernel<<<dim3(32, 32, 1), 256, 0, stream>>>(wq, qkvt,            UDIM, DMODEL, 0, 0);
  transpose_kernel<<<dim3(32, 32, 1), 256, 0, stream>>>(wk, qkvt + 4194304,  UDIM, DMODEL, 0, 0);
  transpose_kernel<<<dim3(32, 32, 1), 256, 0, stream>>>(wv, qkvt + 8388608,  UDIM, DMODEL, 0, 0);
  transpose_kernel<<<dim3(32, 32, 1), 256, 0, stream>>>(wo_, wot, DMODEL, DMODEL, 0, 0);
  concat_bias<<<24, 256, 0, stream>>>(bq, bk, bv, bqkv);

  // fused QKV GEMM: [8192 x 6144 x 2048] (eout dead; qkv region free)
  gemm256<bf16><<<dim3(768), 512, 131072, stream>>>(moeb, qkvt, bqkv, qkv, BTOK, 3 * DMODEL, UDIM);
  attn_kernel<<<2048, 256, 0, stream>>>(qkv, aout);
  // output projection: [8192 x 2048 x 2048] + bo -> fp32 d_out (256 blocks)
  gemm256<float><<<dim3(256), 512, 131072, stream>>>(aout, wot, bo, out, BTOK, DMODEL, 2048);
}